// Round 3
// baseline (1343.943 us; speedup 1.0000x reference)
//
#include <hip/hip_runtime.h>

// ---------------- problem constants ----------------
constexpr int L  = 6;
constexpr int C  = 512;
constexpr int FC = 2048;
constexpr int H  = 8;
constexpr int KC = 64;
constexpr int T  = 1024;
constexpr int B  = 4;
#define SCALE 0.125f   // 1/sqrt(KC)
#define LOG2E 1.4426950408889634f

typedef __bf16 bf16_t;
typedef __bf16 bf16x8 __attribute__((ext_vector_type(8)));
typedef float  f32x4  __attribute__((ext_vector_type(4)));

// ---------------- workspace layout (bytes) ----------------
constexpr size_t OFF_XF    = 0;                               // f32 [B][T][C]      8 MB
constexpr size_t OFF_YF    = OFF_XF   + (size_t)B*T*C*4;      // f32 [B][T][C]      8 MB (partial 0; head 512KB aliases attn m/l)
constexpr size_t OFF_XPAD  = OFF_YF   + (size_t)B*T*C*4;      // bf16 [B][T+2][C]
constexpr size_t OFF_Q     = OFF_XPAD + (size_t)B*(T+2)*C*2;  // bf16 [B][T][C]  (alias: f32 partial 1 spans Q+K)
constexpr size_t OFF_K     = OFF_Q    + (size_t)B*T*C*2;
constexpr size_t OFF_VT    = OFF_K    + (size_t)B*T*C*2;      // bf16 [B][C][T]  (alias: f32 partial 2 spans VT+YA)
constexpr size_t OFF_YA    = OFF_VT   + (size_t)B*T*C*2;      // bf16 [B][T][C]
constexpr size_t OFF_MID   = OFF_YA   + (size_t)B*T*C*2;      // bf16 [B][T+2][FC] 16.81 MB (alias: attn f32 O-partials 16.78 MB)
constexpr size_t OFF_WQKVO = OFF_MID  + (size_t)B*(T+2)*FC*2; // bf16 [4][C][C]
constexpr size_t OFF_W1    = OFF_WQKVO+ (size_t)4*C*C*2;      // bf16 [3][FC][C]
constexpr size_t OFF_W2    = OFF_W1   + (size_t)3*FC*C*2;     // bf16 [3][C][FC]
// total ~69.3 MB

// ---------------- async global->LDS (16B/lane) ----------------
__device__ __forceinline__ void gload_lds16(const bf16_t* g, bf16_t* l) {
    __builtin_amdgcn_global_load_lds((const __attribute__((address_space(1))) void*)g,
                                     (__attribute__((address_space(3))) void*)l, 16, 0, 0);
}

// ---------------- conversion kernels ----------------
__global__ __launch_bounds__(256) void cvt4_kernel(const float* __restrict__ a,
                                                   const float* __restrict__ b,
                                                   const float* __restrict__ c,
                                                   const float* __restrict__ d,
                                                   bf16_t* __restrict__ out) {
    int i = blockIdx.x * 256 + threadIdx.x;      // 4*C*C
    int which = i >> 18;
    int idx   = i & ((1 << 18) - 1);
    const float* s = (which == 0) ? a : (which == 1) ? b : (which == 2) ? c : d;
    out[i] = (bf16_t)s[idx];
}

__global__ __launch_bounds__(256) void cvtw1_kernel(const float* __restrict__ w1, bf16_t* __restrict__ out) {
    int i = blockIdx.x * 256 + threadIdx.x;      // 3*FC*C,   out [3][FC][C]
    int j = i >> 20;
    int rem = i & ((1 << 20) - 1);
    int fc = rem >> 9, c = rem & 511;
    out[i] = (bf16_t)w1[fc * (C * 3) + c * 3 + j];
}

__global__ __launch_bounds__(256) void cvtw2_kernel(const float* __restrict__ w2, bf16_t* __restrict__ out) {
    int i = blockIdx.x * 256 + threadIdx.x;      // 3*C*FC,   out [3][C][FC]
    int j = i >> 20;
    int rem = i & ((1 << 20) - 1);
    int c = rem >> 11, fc = rem & 2047;
    out[i] = (bf16_t)w2[c * (FC * 3) + fc * 3 + j];
}

// ---------------- transpose in/out ----------------
__global__ __launch_bounds__(256) void transpose_in(const float* __restrict__ x0,
                                                    float* __restrict__ xf,
                                                    bf16_t* __restrict__ xpad) {
    __shared__ float tile[32][33];
    int b = blockIdx.z, t0 = blockIdx.x * 32, c0 = blockIdx.y * 32;
    int tx = threadIdx.x, ty = threadIdx.y;
#pragma unroll
    for (int j = 0; j < 4; ++j)
        tile[ty + j * 8][tx] = x0[((size_t)b * C + c0 + ty + j * 8) * T + t0 + tx];
    __syncthreads();
#pragma unroll
    for (int j = 0; j < 4; ++j) {
        float v = tile[tx][ty + j * 8];
        long t = t0 + ty + j * 8;
        xf[((size_t)b * T + t) * C + c0 + tx] = v;
        xpad[((size_t)b * (T + 2) + t + 1) * C + c0 + tx] = (bf16_t)v;
    }
}

__global__ __launch_bounds__(256) void transpose_out(const float* __restrict__ xf,
                                                     float* __restrict__ out) {
    __shared__ float tile[32][33];
    int b = blockIdx.z, t0 = blockIdx.x * 32, c0 = blockIdx.y * 32;
    int tx = threadIdx.x, ty = threadIdx.y;
#pragma unroll
    for (int j = 0; j < 4; ++j)
        tile[ty + j * 8][tx] = xf[((size_t)b * T + t0 + ty + j * 8) * C + c0 + tx];
    __syncthreads();
#pragma unroll
    for (int j = 0; j < 4; ++j)
        out[((size_t)b * C + c0 + ty + j * 8) * T + t0 + tx] = tile[tx][ty + j * 8];
}

// ---------------- zero conv pads ----------------
__global__ __launch_bounds__(256) void zero_pads(bf16_t* __restrict__ xpad, bf16_t* __restrict__ midp) {
    int i = blockIdx.x * 256 + threadIdx.x;
    if (i < 4096) {
        int b = i >> 10, r = (i >> 9) & 1, c = i & 511;
        xpad[((size_t)b * (T + 2) + (size_t)r * (T + 1)) * C + c] = (bf16_t)0.f;
    } else {
        int j = i - 4096;
        int b = j >> 12, r = (j >> 11) & 1, c = j & 2047;
        midp[((size_t)b * (T + 2) + (size_t)r * (T + 1)) * FC + c] = (bf16_t)0.f;
    }
}

// ---------------- residual + NP-partial sum + layernorm (channel dim) ----------------
// ZPAD: first 64 blocks also re-zero the midp conv pad rows (attn partials alias MID)
template <int NP, bool ZPAD>
__global__ __launch_bounds__(256) void add_ln(float* __restrict__ x,
                                              const float* __restrict__ p0, const float* __restrict__ p1,
                                              const float* __restrict__ p2,
                                              const float* __restrict__ g, const float* __restrict__ be,
                                              bf16_t* __restrict__ xpad, bf16_t* __restrict__ midp) {
    long bt = blockIdx.x;
    int tid = threadIdx.x;
    if (ZPAD) {
        if (bt < 64) {   // block-uniform branch; 64*256 = 2*B*FC pad elems
            int idx = (int)bt * 256 + tid;
            int bb = idx >> 12, r = (idx >> 11) & 1, cc = idx & 2047;
            midp[((size_t)bb * (T + 2) + (size_t)r * (T + 1)) * FC + cc] = (bf16_t)0.f;
        }
    }
    float* xr = x + bt * C;
    float v0 = xr[tid] + p0[bt * C + tid] + p1[bt * C + tid];
    float v1 = xr[tid + 256] + p0[bt * C + tid + 256] + p1[bt * C + tid + 256];
    if (NP == 3) { v0 += p2[bt * C + tid]; v1 += p2[bt * C + tid + 256]; }
    float s = v0 + v1, q = v0 * v0 + v1 * v1;
#pragma unroll
    for (int m = 1; m < 64; m <<= 1) { s += __shfl_xor(s, m); q += __shfl_xor(q, m); }
    __shared__ float ss[4], qq[4];
    int wid = tid >> 6;
    if ((tid & 63) == 0) { ss[wid] = s; qq[wid] = q; }
    __syncthreads();
    s = ss[0] + ss[1] + ss[2] + ss[3];
    q = qq[0] + qq[1] + qq[2] + qq[3];
    float mean = s * (1.f / C);
    float var = q * (1.f / C) - mean * mean;
    float rstd = rsqrtf(var + 1e-4f);
    float o0 = (v0 - mean) * rstd * g[tid] + be[tid];
    float o1 = (v1 - mean) * rstd * g[tid + 256] + be[tid + 256];
    xr[tid] = o0; xr[tid + 256] = o1;
    long b = bt >> 10, t = bt & (T - 1);
    bf16_t* xp = xpad + (b * (T + 2) + t + 1) * C;
    xp[tid] = (bf16_t)o0; xp[tid + 256] = (bf16_t)o1;
}

// ---------------- 128x128 GEMM, BK=64, global_load_lds + XOR-swizzled LDS ----------------
template <int OUTMODE, bool RELU, int NSPLIT, int IPT, int NTAPS>
__global__ __launch_bounds__(256) void gemm128(
    const bf16_t* __restrict__ A, long batchStrideA, int lda,
    const bf16_t* __restrict__ Bw, long tapStrideB, int ldb,
    const float* __restrict__ bias0, const float* __restrict__ bias1,
    const float* __restrict__ bias2,
    void* __restrict__ Dp, void* __restrict__ D1p, void* __restrict__ D2p,
    long batchStrideD, int ldd) {
    __shared__ bf16_t As[128 * 64];
    __shared__ bf16_t Bs[128 * 64];
    const int tid = threadIdx.x;
    const int lane = tid & 63, wid = tid >> 6;
    const int l15 = lane & 15, quad = lane >> 4;
    const int wy = wid >> 1, wx = wid & 1;
    const int nb = gridDim.z / NSPLIT;
    const int split = (NSPLIT > 1) ? ((int)blockIdx.z / nb) : 0;
    const int b = (int)blockIdx.z - split * nb;

    const bf16_t* Ab = A + (long)b * batchStrideA + (long)blockIdx.y * 128 * lda;
    const bf16_t* Bb = Bw + (long)blockIdx.x * 128 * ldb;

    const int lrow = lane >> 3;
    const int lcolsw = ((lane & 7) ^ lrow) * 8;

    f32x4 acc[4][4];
#pragma unroll
    for (int i = 0; i < 4; ++i)
#pragma unroll
        for (int j = 0; j < 4; ++j) acc[i][j] = (f32x4){0.f, 0.f, 0.f, 0.f};

    constexpr int itersAll = IPT * NTAPS;
    constexpr int per = itersAll / NSPLIT;
    const int it0 = split * per;

    for (int it = it0; it < it0 + per; ++it) {
        const int tap = (NTAPS == 1) ? 0 : (it / IPT);
        const int k0 = (it - tap * IPT) * 64;
        const bf16_t* At = Ab + (long)tap * lda + k0;
        const bf16_t* Bt = Bb + (long)tap * tapStrideB + k0;
        __syncthreads();
#pragma unroll
        for (int i = 0; i < 4; ++i) {
            int chunk = wid * 4 + i;
            int row = chunk * 8 + lrow;
            gload_lds16(At + (long)row * lda + lcolsw, As + chunk * 512 + lane * 8);
            gload_lds16(Bt + (long)row * ldb + lcolsw, Bs + chunk * 512 + lane * 8);
        }
        __syncthreads();
#pragma unroll
        for (int ks = 0; ks < 2; ++ks) {
            bf16x8 bfr[4], afr[4];
#pragma unroll
            for (int nt = 0; nt < 4; ++nt) {
                int row = wx * 64 + nt * 16 + l15;
                bfr[nt] = *(const bf16x8*)&Bs[row * 64 + (((ks * 4 + quad) ^ (l15 & 7)) * 8)];
            }
#pragma unroll
            for (int mt = 0; mt < 4; ++mt) {
                int row = wy * 64 + mt * 16 + l15;
                afr[mt] = *(const bf16x8*)&As[row * 64 + (((ks * 4 + quad) ^ (l15 & 7)) * 8)];
            }
#pragma unroll
            for (int mt = 0; mt < 4; ++mt)
#pragma unroll
                for (int nt = 0; nt < 4; ++nt)
                    acc[mt][nt] = __builtin_amdgcn_mfma_f32_16x16x32_bf16(afr[mt], bfr[nt], acc[mt][nt], 0, 0, 0);
        }
    }

    const long m0 = (long)blockIdx.y * 128 + wy * 64;
    const int n0g = (int)blockIdx.x * 128 + wx * 64;
#pragma unroll
    for (int mt = 0; mt < 4; ++mt) {
        long rowb = m0 + mt * 16 + quad * 4;
#pragma unroll
        for (int nt = 0; nt < 4; ++nt) {
            int col = n0g + nt * 16 + l15;
            if (OUTMODE == 0) {
                float bb = (split == 0) ? bias0[col] : 0.f;
                float* D = ((split == 0) ? (float*)Dp : (split == 1) ? (float*)D1p : (float*)D2p)
                           + (long)b * batchStrideD;
#pragma unroll
                for (int r = 0; r < 4; ++r) D[(rowb + r) * ldd + col] = acc[mt][nt][r] + bb;
            } else if (OUTMODE == 1) {
                float bb = bias0[col];
                bf16_t* D = (bf16_t*)Dp + (long)b * batchStrideD;
#pragma unroll
                for (int r = 0; r < 4; ++r) {
                    float v = acc[mt][nt][r] + bb;
                    if (RELU) v = fmaxf(v, 0.f);
                    D[(rowb + r) * ldd + col] = (bf16_t)v;
                }
            } else {  // QKV fused
                int which = col >> 9, cl = col & 511;
                const float* bp = (which == 0) ? bias0 : (which == 1) ? bias1 : bias2;
                float bb = bp[cl];
                if (which < 2) {
                    bf16_t* D = (bf16_t*)((which == 0) ? Dp : D1p) + (long)b * T * C;
#pragma unroll
                    for (int r = 0; r < 4; ++r) D[(rowb + r) * C + cl] = (bf16_t)(acc[mt][nt][r] + bb);
                } else {
                    bf16_t* D = (bf16_t*)D2p + (long)b * C * T;
                    union { bf16_t h[4]; uint2 u; } pk;
#pragma unroll
                    for (int r = 0; r < 4; ++r) pk.h[r] = (bf16_t)(acc[mt][nt][r] + bb);
                    *(uint2*)(D + (long)cl * T + rowb) = pk.u;
                }
            }
        }
    }
}

// ---------------- fused attention: 64-row Q tiles, grid-level KV split ----------------
// grid (T/64, H, 2*B), 256 thr (4 waves) — same proven block shape as the 54.7us baseline.
// blockIdx.z = half*B + b: block processes KV rows [half*512, half*512+512) (8 tiles),
// writes unnormalized f32 partial O + (m,l) per row; attn_combine merges the halves.
// LDS 36864 B -> 4 blocks/CU = 16 waves/CU (baseline: 2 blocks = 8 waves).
__global__ __launch_bounds__(256) void attn_kernel(const bf16_t* __restrict__ q,
                                                   const bf16_t* __restrict__ k,
                                                   const bf16_t* __restrict__ vT,
                                                   const float* __restrict__ relk,
                                                   float* __restrict__ op,
                                                   float* __restrict__ mb,
                                                   float* __restrict__ lb) {
    const int z = blockIdx.z;
    const int b = z % B, half = z / B;
    const int h = blockIdx.y;
    const int qt0 = blockIdx.x * 64;
    __shared__ bf16_t qps[64 * 72];      // swizzled Q [64][64] first, then P tile [64][72]
    __shared__ bf16_t ktb[2][64 * 64];   // double-buffered swizzled K tiles
    __shared__ bf16_t vtb[64 * 64];      // single-buffered swizzled V^T tile
    __shared__ float  rl[64][12];        // rel logits (exp2 domain)

    const int tid = threadIdx.x;
    const int lane = tid & 63, wid = tid >> 6;
    const int l15 = lane & 15, quad = lane >> 4;
    const int lrow = lane >> 3;                // 0..7 row within 8-row chunk
    const int su   = ((lane & 7) ^ lrow) * 8;  // swizzled source elem offset

    const bf16_t* qbase = q + ((size_t)(b * T + qt0)) * C + h * 64;
    const bf16_t* kbs = k + ((size_t)(b * T + half * 512)) * C + h * 64;
    const bf16_t* vbs = vT + ((size_t)(b * C + h * 64)) * T + half * 512;

    // prologue: stage Q (8 chunks) + K tile 0, all async
#pragma unroll
    for (int i = 0; i < 2; ++i) {
        int chunk = wid * 2 + i;
        int row = chunk * 8 + lrow;
        gload_lds16(qbase + (long)row * C + su, qps + chunk * 512 + lane * 8);
        gload_lds16(kbs + (long)row * C + su, ktb[0] + chunk * 512 + lane * 8);
    }
    __syncthreads();

    // rel logits: rl[r][j] = (SCALE*LOG2E) * q[r]·relk[j]   (reads swizzled qps)
    for (int i = tid; i < 64 * 9; i += 256) {
        int r = i / 9, j = i - r * 9;
        float acc = 0.f;
#pragma unroll
        for (int d = 0; d < 64; ++d)
            acc += (float)qps[r * 64 + ((d >> 3) ^ (r & 7)) * 8 + (d & 7)] * relk[j * 64 + d];
        rl[r][j] = acc * (SCALE * LOG2E);
    }

    // Q fragments: wave rows wid*16..wid*16+15
    bf16x8 af[2];
#pragma unroll
    for (int ks = 0; ks < 2; ++ks) {
        int r = wid * 16 + l15;
        af[ks] = *(const bf16x8*)&qps[r * 64 + (((ks * 4 + quad) ^ (r & 7)) * 8)];
    }

    float m_i[4], l_i[4];
    f32x4 o[4];
#pragma unroll
    for (int r = 0; r < 4; ++r) { m_i[r] = -1e30f; l_i[r] = 0.f; }
#pragma unroll
    for (int dn = 0; dn < 4; ++dn) o[dn] = (f32x4){0.f, 0.f, 0.f, 0.f};

    for (int st = 0; st < 8; ++st) {
        // barrier A: prev iter's PV done (V buffer free), K(st) staged last iter now drained,
        // rl/af phase done (st==0) so qps is free for P
        __syncthreads();
        {
            const bf16_t* vb = vbs + st * 64;
#pragma unroll
            for (int i = 0; i < 2; ++i) {
                int chunk = wid * 2 + i, row = chunk * 8 + lrow;
                gload_lds16(vb + (long)row * T + su, vtb + chunk * 512 + lane * 8);
            }
        }
        if (st < 7) {
            const bf16_t* kb2 = kbs + (size_t)(st + 1) * 64 * C;
#pragma unroll
            for (int i = 0; i < 2; ++i) {
                int chunk = wid * 2 + i, row = chunk * 8 + lrow;
                gload_lds16(kb2 + (long)row * C + su, ktb[(st + 1) & 1] + chunk * 512 + lane * 8);
            }
        }
        const bf16_t* ktc = ktb[st & 1];

        // scores: 16x64 per wave = 4 n-tiles
        f32x4 sc[4];
#pragma unroll
        for (int nt = 0; nt < 4; ++nt) {
            f32x4 a = (f32x4){0.f, 0.f, 0.f, 0.f};
#pragma unroll
            for (int ks = 0; ks < 2; ++ks) {
                int rr = nt * 16 + l15;
                bf16x8 bfr = *(const bf16x8*)&ktc[rr * 64 + (((ks * 4 + quad) ^ (l15 & 7)) * 8)];
                a = __builtin_amdgcn_mfma_f32_16x16x32_bf16(af[ks], bfr, a, 0, 0, 0);
            }
            sc[nt] = a;
        }

        // scale (exp2 domain) + rel bias
#pragma unroll
        for (int nt = 0; nt < 4; ++nt)
#pragma unroll
            for (int r = 0; r < 4; ++r) {
                int row = wid * 16 + quad * 4 + r;
                int j = (half * 512 + st * 64 + nt * 16 + l15) - (qt0 + row) + 4;
                j = j < 0 ? 0 : (j > 8 ? 8 : j);
                sc[nt][r] = sc[nt][r] * (SCALE * LOG2E) + rl[row][j];
            }

        // online softmax (base 2)
        float alpha[4];
#pragma unroll
        for (int r = 0; r < 4; ++r) {
            float mx = fmaxf(fmaxf(sc[0][r], sc[1][r]), fmaxf(sc[2][r], sc[3][r]));
#pragma unroll
            for (int d = 1; d < 16; d <<= 1) mx = fmaxf(mx, __shfl_xor(mx, d));
            float mn = fmaxf(m_i[r], mx);
            alpha[r] = exp2f(m_i[r] - mn);
            m_i[r] = mn;
        }
#pragma unroll
        for (int r = 0; r < 4; ++r) {
            float rs = 0.f;
#pragma unroll
            for (int nt = 0; nt < 4; ++nt) {
                float p = exp2f(sc[nt][r] - m_i[r]);
                sc[nt][r] = p;
                rs += p;
            }
#pragma unroll
            for (int d = 1; d < 16; d <<= 1) rs += __shfl_xor(rs, d);
            l_i[r] = l_i[r] * alpha[r] + rs;
        }
#pragma unroll
        for (int dn = 0; dn < 4; ++dn)
#pragma unroll
            for (int r = 0; r < 4; ++r) o[dn][r] *= alpha[r];

        // barrier B: V(st) (and K(st+1)) staged & vmcnt-drained for all waves
        __syncthreads();

        // P through LDS (wave-private rows; C-layout -> A-layout)
#pragma unroll
        for (int nt = 0; nt < 4; ++nt)
#pragma unroll
            for (int r = 0; r < 4; ++r)
                qps[(wid * 16 + quad * 4 + r) * 72 + nt * 16 + l15] = (bf16_t)sc[nt][r];

        bf16x8 pa[2];
#pragma unroll
        for (int ks = 0; ks < 2; ++ks)
            pa[ks] = *(const bf16x8*)&qps[(wid * 16 + l15) * 72 + ks * 32 + quad * 8];
#pragma unroll
        for (int dn = 0; dn < 4; ++dn)
#pragma unroll
            for (int ks = 0; ks < 2; ++ks) {
                int rr = dn * 16 + l15;
                bf16x8 vf = *(const bf16x8*)&vtb[rr * 64 + (((ks * 4 + quad) ^ (l15 & 7)) * 8)];
                o[dn] = __builtin_amdgcn_mfma_f32_16x16x32_bf16(pa[ks], vf, o[dn], 0, 0, 0);
            }
    }

    // epilogue: unnormalized partials + (m,l)
    float* opb = op + ((size_t)((half * B + b) * T + qt0)) * C + h * 64;
    float* mptr = mb + ((size_t)((half * B + b) * H + h)) * T + qt0;
    float* lptr = lb + ((size_t)((half * B + b) * H + h)) * T + qt0;
#pragma unroll
    for (int r = 0; r < 4; ++r) {
        int row = wid * 16 + quad * 4 + r;
#pragma unroll
        for (int dn = 0; dn < 4; ++dn)
            opb[(long)row * C + dn * 16 + l15] = o[dn][r];
        if (l15 == 0) { mptr[row] = m_i[r]; lptr[row] = l_i[r]; }
    }
}

// ---------------- flash-combine of the two KV halves ----------------
// grid B*T blocks, 256 thr; each thread merges 2 channels via float2 loads.
__global__ __launch_bounds__(256) void attn_combine(const float* __restrict__ op,
                                                    const float* __restrict__ mb,
                                                    const float* __restrict__ lb,
                                                    bf16_t* __restrict__ y) {
    int bt = blockIdx.x;                  // [0, B*T)
    int b = bt >> 10, t = bt & (T - 1);
    int tid = threadIdx.x;
    int h = tid >> 5;                     // c0 = 2*tid -> h = c0/64
    size_t mi0 = ((size_t)(b)*H + h) * T + t;
    size_t mi1 = ((size_t)(B + b) * H + h) * T + t;
    float m0 = mb[mi0], l0 = lb[mi0];
    float m1 = mb[mi1], l1 = lb[mi1];
    float mm = fmaxf(m0, m1);
    float a0 = exp2f(m0 - mm), a1 = exp2f(m1 - mm);
    float linv = 1.f / (l0 * a0 + l1 * a1);
    float2 o0 = *((const float2*)(op + ((size_t)b * T + t) * C) + tid);
    float2 o1 = *((const float2*)(op + ((size_t)(B + b) * T + t) * C) + tid);
    union { bf16_t h2[2]; unsigned u; } pk;
    pk.h2[0] = (bf16_t)((o0.x * a0 + o1.x * a1) * linv);
    pk.h2[1] = (bf16_t)((o0.y * a0 + o1.y * a1) * linv);
    ((unsigned*)(y + ((size_t)(b * T + t)) * C))[tid] = pk.u;
}

// ---------------- host launch ----------------
extern "C" void kernel_launch(void* const* d_in, const int* in_sizes, int n_in,
                              void* d_out, int out_size, void* d_ws, size_t ws_size,
                              hipStream_t stream) {
    const float* x0  = (const float*)d_in[0];
    const float* wq  = (const float*)d_in[1];
    const float* bq  = (const float*)d_in[2];
    const float* wk  = (const float*)d_in[3];
    const float* bk  = (const float*)d_in[4];
    const float* wv  = (const float*)d_in[5];
    const float* bv  = (const float*)d_in[6];
    const float* wo  = (const float*)d_in[7];
    const float* bo  = (const float*)d_in[8];
    const float* rlk = (const float*)d_in[9];
    const float* g1  = (const float*)d_in[10];
    const float* be1 = (const float*)d_in[11];
    const float* w1  = (const float*)d_in[12];
    const float* bb1 = (const float*)d_in[13];
    const float* w2  = (const float*)d_in[14];
    const float* bb2 = (const float*)d_in[15];
    const float* g2  = (const float*)d_in[16];
    const float* be2 = (const float*)d_in[17];

    char* ws = (char*)d_ws;
    float*  xf    = (float*)(ws + OFF_XF);
    float*  yf    = (float*)(ws + OFF_YF);
    float*  yf2   = (float*)(ws + OFF_Q);       // aliases Q+K (dead at use time)
    float*  yf3   = (float*)(ws + OFF_VT);      // aliases VT+YA (dead during FFN2)
    bf16_t* xpad  = (bf16_t*)(ws + OFF_XPAD);
    bf16_t* qb    = (bf16_t*)(ws + OFF_Q);
    bf16_t* kb    = (bf16_t*)(ws + OFF_K);
    bf16_t* vTb   = (bf16_t*)(ws + OFF_VT);
    bf16_t* yab   = (bf16_t*)(ws + OFF_YA);
    bf16_t* midp  = (bf16_t*)(ws + OFF_MID);
    bf16_t* wqkvo = (bf16_t*)(ws + OFF_WQKVO);
    bf16_t* w1b   = (bf16_t*)(ws + OFF_W1);
    bf16_t* w2b   = (bf16_t*)(ws + OFF_W2);
    // attn partials alias dead regions during the attn+combine window:
    float*  opart = (float*)(ws + OFF_MID);     // [2][B][T][C] f32 = 16.78 MB <= MID (16.81 MB)
    float*  mpart = (float*)(ws + OFF_YF);      // [2][B][H][T] f32 = 256 KB
    float*  lpart = mpart + (size_t)2 * B * H * T;

    transpose_in<<<dim3(T / 32, C / 32, B), dim3(32, 8), 0, stream>>>(x0, xf, xpad);
    zero_pads<<<80, 256, 0, stream>>>(xpad, midp);

    for (int l = 0; l < L; ++l) {
        cvt4_kernel<<<4 * C * C / 256, 256, 0, stream>>>(wq + (size_t)l * C * C, wk + (size_t)l * C * C,
                                                         wv + (size_t)l * C * C, wo + (size_t)l * C * C, wqkvo);
        cvtw1_kernel<<<3 * FC * C / 256, 256, 0, stream>>>(w1 + (size_t)l * FC * C * 3, w1b);
        cvtw2_kernel<<<3 * C * FC / 256, 256, 0, stream>>>(w2 + (size_t)l * C * FC * 3, w2b);

        // fused QKV projection: N=1536, K=512 -> qb, kb, vT
        gemm128<3, false, 1, 8, 1><<<dim3(1536 / 128, T / 128, B), 256, 0, stream>>>(
            xpad + C, (long)(T + 2) * C, C, wqkvo, 0, C,
            bq + l * C, bk + l * C, bv + l * C,
            (void*)qb, (void*)kb, (void*)vTb, 0, 0);

        attn_kernel<<<dim3(T / 64, H, 2 * B), 256, 0, stream>>>(qb, kb, vTb, rlk + (size_t)l * 9 * KC,
                                                                opart, mpart, lpart);
        attn_combine<<<B * T, 256, 0, stream>>>(opart, mpart, lpart, yab);

        // O projection, split-K x2 -> f32 partials yf, yf2
        gemm128<0, false, 2, 8, 1><<<dim3(C / 128, T / 128, 2 * B), 256, 0, stream>>>(
            yab, (long)T * C, C, wqkvo + 3 * C * C, 0, C,
            bo + l * C, nullptr, nullptr,
            (void*)yf, (void*)yf2, nullptr, (long)T * C, C);

        add_ln<2, true><<<B * T, 256, 0, stream>>>(xf, yf, yf2, nullptr, g1 + l * C, be1 + l * C, xpad, midp);

        // FFN1: conv K=3 + bias + relu -> bf16 mid_pad rows 1..T
        gemm128<1, true, 1, 8, 3><<<dim3(FC / 128, T / 128, B), 256, 0, stream>>>(
            xpad, (long)(T + 2) * C, C, w1b, (long)FC * C, C,
            bb1 + l * FC, nullptr, nullptr,
            (void*)(midp + FC), nullptr, nullptr, (long)(T + 2) * FC, FC);

        // FFN2: conv K=3, split-K x3 (tap-aligned) -> f32 partials yf, yf2, yf3
        gemm128<0, false, 3, 32, 3><<<dim3(C / 128, T / 128, 3 * B), 256, 0, stream>>>(
            midp, (long)(T + 2) * FC, FC, w2b, (long)C * FC, FC,
            bb2 + l * C, nullptr, nullptr,
            (void*)yf, (void*)yf2, (void*)yf3, (long)T * C, C);

        add_ln<3, false><<<B * T, 256, 0, stream>>>(xf, yf, yf2, yf3, g2 + l * C, be2 + l * C, xpad, nullptr);
    }

    transpose_out<<<dim3(T / 32, C / 32, B), dim3(32, 8), 0, stream>>>(xf, (float*)d_out);
}

// Round 4
// 1238.513 us; speedup vs baseline: 1.0851x; 1.0851x over previous
//
#include <hip/hip_runtime.h>

// ---------------- problem constants ----------------
constexpr int L  = 6;
constexpr int C  = 512;
constexpr int FC = 2048;
constexpr int H  = 8;
constexpr int KC = 64;
constexpr int T  = 1024;
constexpr int B  = 4;
#define SCALE 0.125f   // 1/sqrt(KC)
#define LOG2E 1.4426950408889634f

typedef __bf16 bf16_t;
typedef __bf16 bf16x8 __attribute__((ext_vector_type(8)));
typedef float  f32x4  __attribute__((ext_vector_type(4)));

// ---------------- workspace layout (bytes) ----------------
constexpr size_t OFF_XF    = 0;                               // f32 [B][T][C]      8 MB
constexpr size_t OFF_YF    = OFF_XF   + (size_t)B*T*C*4;      // f32 [B][T][C]      8 MB (partial 0)
constexpr size_t OFF_XPAD  = OFF_YF   + (size_t)B*T*C*4;      // bf16 [B][T+2][C]
constexpr size_t OFF_Q     = OFF_XPAD + (size_t)B*(T+2)*C*2;  // bf16 [B][T][C]  (alias: f32 partial 1 spans Q+K)
constexpr size_t OFF_K     = OFF_Q    + (size_t)B*T*C*2;
constexpr size_t OFF_VT    = OFF_K    + (size_t)B*T*C*2;      // bf16 [B][C][T]  (alias: f32 partial 2 spans VT+YA)
constexpr size_t OFF_YA    = OFF_VT   + (size_t)B*T*C*2;      // bf16 [B][T][C]
constexpr size_t OFF_MID   = OFF_YA   + (size_t)B*T*C*2;      // bf16 [B][T+2][FC]  16 MB
constexpr size_t OFF_WQKVO = OFF_MID  + (size_t)B*(T+2)*FC*2; // bf16 [4][C][C]
constexpr size_t OFF_W1    = OFF_WQKVO+ (size_t)4*C*C*2;      // bf16 [3][FC][C]
constexpr size_t OFF_W2    = OFF_W1   + (size_t)3*FC*C*2;     // bf16 [3][C][FC]
// total ~69.3 MB

// ---------------- async global->LDS (16B/lane) ----------------
__device__ __forceinline__ void gload_lds16(const bf16_t* g, bf16_t* l) {
    __builtin_amdgcn_global_load_lds((const __attribute__((address_space(1))) void*)g,
                                     (__attribute__((address_space(3))) void*)l, 16, 0, 0);
}

// ---------------- conversion kernels ----------------
__global__ __launch_bounds__(256) void cvt4_kernel(const float* __restrict__ a,
                                                   const float* __restrict__ b,
                                                   const float* __restrict__ c,
                                                   const float* __restrict__ d,
                                                   bf16_t* __restrict__ out) {
    int i = blockIdx.x * 256 + threadIdx.x;      // 4*C*C
    int which = i >> 18;
    int idx   = i & ((1 << 18) - 1);
    const float* s = (which == 0) ? a : (which == 1) ? b : (which == 2) ? c : d;
    out[i] = (bf16_t)s[idx];
}

__global__ __launch_bounds__(256) void cvtw1_kernel(const float* __restrict__ w1, bf16_t* __restrict__ out) {
    int i = blockIdx.x * 256 + threadIdx.x;      // 3*FC*C,   out [3][FC][C]
    int j = i >> 20;
    int rem = i & ((1 << 20) - 1);
    int fc = rem >> 9, c = rem & 511;
    out[i] = (bf16_t)w1[fc * (C * 3) + c * 3 + j];
}

__global__ __launch_bounds__(256) void cvtw2_kernel(const float* __restrict__ w2, bf16_t* __restrict__ out) {
    int i = blockIdx.x * 256 + threadIdx.x;      // 3*C*FC,   out [3][C][FC]
    int j = i >> 20;
    int rem = i & ((1 << 20) - 1);
    int c = rem >> 11, fc = rem & 2047;
    out[i] = (bf16_t)w2[c * (FC * 3) + fc * 3 + j];
}

// ---------------- transpose in/out ----------------
__global__ __launch_bounds__(256) void transpose_in(const float* __restrict__ x0,
                                                    float* __restrict__ xf,
                                                    bf16_t* __restrict__ xpad) {
    __shared__ float tile[32][33];
    int b = blockIdx.z, t0 = blockIdx.x * 32, c0 = blockIdx.y * 32;
    int tx = threadIdx.x, ty = threadIdx.y;
#pragma unroll
    for (int j = 0; j < 4; ++j)
        tile[ty + j * 8][tx] = x0[((size_t)b * C + c0 + ty + j * 8) * T + t0 + tx];
    __syncthreads();
#pragma unroll
    for (int j = 0; j < 4; ++j) {
        float v = tile[tx][ty + j * 8];
        long t = t0 + ty + j * 8;
        xf[((size_t)b * T + t) * C + c0 + tx] = v;
        xpad[((size_t)b * (T + 2) + t + 1) * C + c0 + tx] = (bf16_t)v;
    }
}

__global__ __launch_bounds__(256) void transpose_out(const float* __restrict__ xf,
                                                     float* __restrict__ out) {
    __shared__ float tile[32][33];
    int b = blockIdx.z, t0 = blockIdx.x * 32, c0 = blockIdx.y * 32;
    int tx = threadIdx.x, ty = threadIdx.y;
#pragma unroll
    for (int j = 0; j < 4; ++j)
        tile[ty + j * 8][tx] = xf[((size_t)b * T + t0 + ty + j * 8) * C + c0 + tx];
    __syncthreads();
#pragma unroll
    for (int j = 0; j < 4; ++j)
        out[((size_t)b * C + c0 + ty + j * 8) * T + t0 + tx] = tile[tx][ty + j * 8];
}

// ---------------- zero conv pads ----------------
__global__ __launch_bounds__(256) void zero_pads(bf16_t* __restrict__ xpad, bf16_t* __restrict__ midp) {
    int i = blockIdx.x * 256 + threadIdx.x;
    if (i < 4096) {
        int b = i >> 10, r = (i >> 9) & 1, c = i & 511;
        xpad[((size_t)b * (T + 2) + (size_t)r * (T + 1)) * C + c] = (bf16_t)0.f;
    } else {
        int j = i - 4096;
        int b = j >> 12, r = (j >> 11) & 1, c = j & 2047;
        midp[((size_t)b * (T + 2) + (size_t)r * (T + 1)) * FC + c] = (bf16_t)0.f;
    }
}

// ---------------- residual + NP-partial sum + layernorm (channel dim) ----------------
template <int NP>
__global__ __launch_bounds__(256) void add_ln(float* __restrict__ x,
                                              const float* __restrict__ p0, const float* __restrict__ p1,
                                              const float* __restrict__ p2,
                                              const float* __restrict__ g, const float* __restrict__ be,
                                              bf16_t* __restrict__ xpad) {
    long bt = blockIdx.x;
    int tid = threadIdx.x;
    float* xr = x + bt * C;
    float v0 = xr[tid] + p0[bt * C + tid] + p1[bt * C + tid];
    float v1 = xr[tid + 256] + p0[bt * C + tid + 256] + p1[bt * C + tid + 256];
    if (NP == 3) { v0 += p2[bt * C + tid]; v1 += p2[bt * C + tid + 256]; }
    float s = v0 + v1, q = v0 * v0 + v1 * v1;
#pragma unroll
    for (int m = 1; m < 64; m <<= 1) { s += __shfl_xor(s, m); q += __shfl_xor(q, m); }
    __shared__ float ss[4], qq[4];
    int wid = tid >> 6;
    if ((tid & 63) == 0) { ss[wid] = s; qq[wid] = q; }
    __syncthreads();
    s = ss[0] + ss[1] + ss[2] + ss[3];
    q = qq[0] + qq[1] + qq[2] + qq[3];
    float mean = s * (1.f / C);
    float var = q * (1.f / C) - mean * mean;
    float rstd = rsqrtf(var + 1e-4f);
    float o0 = (v0 - mean) * rstd * g[tid] + be[tid];
    float o1 = (v1 - mean) * rstd * g[tid + 256] + be[tid + 256];
    xr[tid] = o0; xr[tid + 256] = o1;
    long b = bt >> 10, t = bt & (T - 1);
    bf16_t* xp = xpad + (b * (T + 2) + t + 1) * C;
    xp[tid] = (bf16_t)o0; xp[tid + 256] = (bf16_t)o1;
}

// ---------------- 128x128 GEMM, BK=64, global_load_lds + XOR-swizzled LDS ----------------
template <int OUTMODE, bool RELU, int NSPLIT, int IPT, int NTAPS>
__global__ __launch_bounds__(256) void gemm128(
    const bf16_t* __restrict__ A, long batchStrideA, int lda,
    const bf16_t* __restrict__ Bw, long tapStrideB, int ldb,
    const float* __restrict__ bias0, const float* __restrict__ bias1,
    const float* __restrict__ bias2,
    void* __restrict__ Dp, void* __restrict__ D1p, void* __restrict__ D2p,
    long batchStrideD, int ldd) {
    __shared__ bf16_t As[128 * 64];
    __shared__ bf16_t Bs[128 * 64];
    const int tid = threadIdx.x;
    const int lane = tid & 63, wid = tid >> 6;
    const int l15 = lane & 15, quad = lane >> 4;
    const int wy = wid >> 1, wx = wid & 1;
    const int nb = gridDim.z / NSPLIT;
    const int split = (NSPLIT > 1) ? ((int)blockIdx.z / nb) : 0;
    const int b = (int)blockIdx.z - split * nb;

    const bf16_t* Ab = A + (long)b * batchStrideA + (long)blockIdx.y * 128 * lda;
    const bf16_t* Bb = Bw + (long)blockIdx.x * 128 * ldb;

    const int lrow = lane >> 3;
    const int lcolsw = ((lane & 7) ^ lrow) * 8;

    f32x4 acc[4][4];
#pragma unroll
    for (int i = 0; i < 4; ++i)
#pragma unroll
        for (int j = 0; j < 4; ++j) acc[i][j] = (f32x4){0.f, 0.f, 0.f, 0.f};

    constexpr int itersAll = IPT * NTAPS;
    constexpr int per = itersAll / NSPLIT;
    const int it0 = split * per;

    for (int it = it0; it < it0 + per; ++it) {
        const int tap = (NTAPS == 1) ? 0 : (it / IPT);
        const int k0 = (it - tap * IPT) * 64;
        const bf16_t* At = Ab + (long)tap * lda + k0;
        const bf16_t* Bt = Bb + (long)tap * tapStrideB + k0;
        __syncthreads();
#pragma unroll
        for (int i = 0; i < 4; ++i) {
            int chunk = wid * 4 + i;
            int row = chunk * 8 + lrow;
            gload_lds16(At + (long)row * lda + lcolsw, As + chunk * 512 + lane * 8);
            gload_lds16(Bt + (long)row * ldb + lcolsw, Bs + chunk * 512 + lane * 8);
        }
        __syncthreads();
#pragma unroll
        for (int ks = 0; ks < 2; ++ks) {
            bf16x8 bfr[4], afr[4];
#pragma unroll
            for (int nt = 0; nt < 4; ++nt) {
                int row = wx * 64 + nt * 16 + l15;
                bfr[nt] = *(const bf16x8*)&Bs[row * 64 + (((ks * 4 + quad) ^ (l15 & 7)) * 8)];
            }
#pragma unroll
            for (int mt = 0; mt < 4; ++mt) {
                int row = wy * 64 + mt * 16 + l15;
                afr[mt] = *(const bf16x8*)&As[row * 64 + (((ks * 4 + quad) ^ (l15 & 7)) * 8)];
            }
#pragma unroll
            for (int mt = 0; mt < 4; ++mt)
#pragma unroll
                for (int nt = 0; nt < 4; ++nt)
                    acc[mt][nt] = __builtin_amdgcn_mfma_f32_16x16x32_bf16(afr[mt], bfr[nt], acc[mt][nt], 0, 0, 0);
        }
    }

    const long m0 = (long)blockIdx.y * 128 + wy * 64;
    const int n0g = (int)blockIdx.x * 128 + wx * 64;
#pragma unroll
    for (int mt = 0; mt < 4; ++mt) {
        long rowb = m0 + mt * 16 + quad * 4;
#pragma unroll
        for (int nt = 0; nt < 4; ++nt) {
            int col = n0g + nt * 16 + l15;
            if (OUTMODE == 0) {
                float bb = (split == 0) ? bias0[col] : 0.f;
                float* D = ((split == 0) ? (float*)Dp : (split == 1) ? (float*)D1p : (float*)D2p)
                           + (long)b * batchStrideD;
#pragma unroll
                for (int r = 0; r < 4; ++r) D[(rowb + r) * ldd + col] = acc[mt][nt][r] + bb;
            } else if (OUTMODE == 1) {
                float bb = bias0[col];
                bf16_t* D = (bf16_t*)Dp + (long)b * batchStrideD;
#pragma unroll
                for (int r = 0; r < 4; ++r) {
                    float v = acc[mt][nt][r] + bb;
                    if (RELU) v = fmaxf(v, 0.f);
                    D[(rowb + r) * ldd + col] = (bf16_t)v;
                }
            } else {  // QKV fused
                int which = col >> 9, cl = col & 511;
                const float* bp = (which == 0) ? bias0 : (which == 1) ? bias1 : bias2;
                float bb = bp[cl];
                if (which < 2) {
                    bf16_t* D = (bf16_t*)((which == 0) ? Dp : D1p) + (long)b * T * C;
#pragma unroll
                    for (int r = 0; r < 4; ++r) D[(rowb + r) * C + cl] = (bf16_t)(acc[mt][nt][r] + bb);
                } else {
                    bf16_t* D = (bf16_t*)D2p + (long)b * C * T;
                    union { bf16_t h[4]; uint2 u; } pk;
#pragma unroll
                    for (int r = 0; r < 4; ++r) pk.h[r] = (bf16_t)(acc[mt][nt][r] + bb);
                    *(uint2*)(D + (long)cl * T + rowb) = pk.u;
                }
            }
        }
    }
}

// ---------------- fused attention: swapped-operand (S^T / O^T) flash kernel ----------------
// grid (T/64, H, B), 256 thr. Wave owns Q rows wid*16..+15. Computes S^T = mfma(K,Q) so each
// lane holds 16 scores of ONE Q row (q = l15): softmax max/sum = in-register tree + 2 shfls;
// m/l/alpha are lane scalars. PV swapped too: O^T = mfma(V, P) — all LDS reads byte-identical
// to the non-swapped version. Rel-bias uniform (j=0 or 8) for 10/16 tiles -> register bias.
__global__ __launch_bounds__(256) void attn_kernel(const bf16_t* __restrict__ q,
                                                   const bf16_t* __restrict__ k,
                                                   const bf16_t* __restrict__ vT,
                                                   const float* __restrict__ relk,
                                                   bf16_t* __restrict__ y) {
    const int b = blockIdx.z, h = blockIdx.y;
    const int qt0 = blockIdx.x * 64;
    __shared__ bf16_t qps[64 * 72];      // swizzled Q [64][64] first, then P strips [8w][16][72]
    __shared__ bf16_t ktb[2][64 * 64];   // double-buffered swizzled K tiles
    __shared__ bf16_t vtb[2][64 * 64];   // double-buffered swizzled V^T tiles
    __shared__ float  rl[64][12];        // rel logits (exp2 domain)

    const int tid = threadIdx.x;
    const int lane = tid & 63, wid = tid >> 6;
    const int l15 = lane & 15, quad = lane >> 4;
    const int lrow = lane >> 3;                // 0..7 row within 8-row chunk
    const int su   = ((lane & 7) ^ lrow) * 8;  // swizzled source elem offset

    const bf16_t* qbase = q + ((size_t)(b * T + qt0)) * C + h * 64;
    const bf16_t* kbs = k + ((size_t)(b * T)) * C + h * 64;
    const bf16_t* vbs = vT + ((size_t)(b * C + h * 64)) * T;

    // prologue: stage Q + K/V tile 0, all async
#pragma unroll
    for (int i = 0; i < 2; ++i) {
        int chunk = wid * 2 + i;
        int row = chunk * 8 + lrow;
        gload_lds16(qbase + (long)row * C + su, qps + chunk * 512 + lane * 8);
        gload_lds16(kbs + (long)row * C + su, ktb[0] + chunk * 512 + lane * 8);
        gload_lds16(vbs + (long)row * T + su, vtb[0] + chunk * 512 + lane * 8);
    }
    __syncthreads();

    // rel logits: rl[r][j] = (SCALE*LOG2E) * q[r]·relk[j]   (reads swizzled qps)
    for (int i = tid; i < 64 * 9; i += 256) {
        int r = i / 9, j = i - r * 9;
        float acc = 0.f;
#pragma unroll
        for (int d = 0; d < 64; ++d)
            acc += (float)qps[r * 64 + ((d >> 3) ^ (r & 7)) * 8 + (d & 7)] * relk[j * 64 + d];
        rl[r][j] = acc * (SCALE * LOG2E);
    }
    __syncthreads();   // rl visible to all threads

    // Q fragments (B-operand role: col = q = l15 of wave's 16-row strip)
    const int qrow = wid * 16 + l15;
    bf16x8 af[2];
#pragma unroll
    for (int ks = 0; ks < 2; ++ks)
        af[ks] = *(const bf16x8*)&qps[qrow * 64 + (((ks * 4 + quad) ^ (qrow & 7)) * 8)];
    const float rl0 = rl[qrow][0], rl8 = rl[qrow][8];   // uniform-tile biases (register)

    float m_i = -1e30f, l_i = 0.f;   // lane-scalar online-softmax state (q = qrow)
    f32x4 o[4];
#pragma unroll
    for (int dn = 0; dn < 4; ++dn) o[dn] = (f32x4){0.f, 0.f, 0.f, 0.f};

    bf16_t* myP = qps + wid * (16 * 72);

    for (int st = 0; st < T / 64; ++st) {
        // barrier: stage(st) drained; prior reads of other dbuf done; (st==0) Q/rl phase done
        __syncthreads();
        if (st < T / 64 - 1) {
            const bf16_t* kb2 = kbs + (size_t)(st + 1) * 64 * C;
            const bf16_t* vb2 = vbs + (st + 1) * 64;
            bf16_t* kd = ktb[(st + 1) & 1];
            bf16_t* vd = vtb[(st + 1) & 1];
#pragma unroll
            for (int i = 0; i < 2; ++i) {
                int chunk = wid * 2 + i, row = chunk * 8 + lrow;
                gload_lds16(kb2 + (long)row * C + su, kd + chunk * 512 + lane * 8);
                gload_lds16(vb2 + (long)row * T + su, vd + chunk * 512 + lane * 8);
            }
        }
        const bf16_t* ktc = ktb[st & 1];
        const bf16_t* vtc = vtb[st & 1];

        // S^T tile: sc[nt][r] = S[s = nt*16 + quad*4 + r][q = l15]  (A=K, B=Q)
        f32x4 sc[4];
#pragma unroll
        for (int nt = 0; nt < 4; ++nt) {
            f32x4 a = (f32x4){0.f, 0.f, 0.f, 0.f};
#pragma unroll
            for (int ks = 0; ks < 2; ++ks) {
                int rr = nt * 16 + l15;
                bf16x8 kfr = *(const bf16x8*)&ktc[rr * 64 + (((ks * 4 + quad) ^ (l15 & 7)) * 8)];
                a = __builtin_amdgcn_mfma_f32_16x16x32_bf16(kfr, af[ks], a, 0, 0, 0);
            }
            sc[nt] = a;
        }

        // scale (exp2 domain) + rel bias.  d = s_g - q_g; j = clamp(d+4, 0, 8).
        // base is a multiple of 16; element d in [base-15, base+63]:
        //   base >= 32  -> all j = 8;  base <= -80 -> all j = 0; else per-element.
        const int base = st * 64 - qt0 - wid * 16;
        if (base >= 32) {
#pragma unroll
            for (int nt = 0; nt < 4; ++nt)
#pragma unroll
                for (int r = 0; r < 4; ++r) sc[nt][r] = sc[nt][r] * (SCALE * LOG2E) + rl8;
        } else if (base <= -80) {
#pragma unroll
            for (int nt = 0; nt < 4; ++nt)
#pragma unroll
                for (int r = 0; r < 4; ++r) sc[nt][r] = sc[nt][r] * (SCALE * LOG2E) + rl0;
        } else {
#pragma unroll
            for (int nt = 0; nt < 4; ++nt)
#pragma unroll
                for (int r = 0; r < 4; ++r) {
                    int j = base + nt * 16 + quad * 4 + r - l15 + 4;
                    j = j < 0 ? 0 : (j > 8 ? 8 : j);
                    sc[nt][r] = sc[nt][r] * (SCALE * LOG2E) + rl[qrow][j];
                }
        }

        // online softmax (base 2): 16 values in-lane + cross-quad combine (xor16, xor32)
        float mx = fmaxf(fmaxf(fmaxf(sc[0][0], sc[0][1]), fmaxf(sc[0][2], sc[0][3])),
                         fmaxf(fmaxf(sc[1][0], sc[1][1]), fmaxf(sc[1][2], sc[1][3])));
        mx = fmaxf(mx, fmaxf(fmaxf(fmaxf(sc[2][0], sc[2][1]), fmaxf(sc[2][2], sc[2][3])),
                             fmaxf(fmaxf(sc[3][0], sc[3][1]), fmaxf(sc[3][2], sc[3][3]))));
        mx = fmaxf(mx, __shfl_xor(mx, 16));
        mx = fmaxf(mx, __shfl_xor(mx, 32));
        float mn = fmaxf(m_i, mx);
        float alpha = exp2f(m_i - mn);
        m_i = mn;
        float rs = 0.f;
#pragma unroll
        for (int nt = 0; nt < 4; ++nt)
#pragma unroll
            for (int r = 0; r < 4; ++r) {
                float p = exp2f(sc[nt][r] - m_i);
                sc[nt][r] = p;
                rs += p;
            }
        rs += __shfl_xor(rs, 16);
        rs += __shfl_xor(rs, 32);
        l_i = l_i * alpha + rs;
#pragma unroll
        for (int dn = 0; dn < 4; ++dn) o[dn] *= alpha;

        // P strip: myP[q=l15][s] — packed 4 x ds_write_b64 (s = nt*16 + quad*4 + r)
#pragma unroll
        for (int nt = 0; nt < 4; ++nt) {
            union { bf16_t hh[4]; uint2 u; } pk;
#pragma unroll
            for (int r = 0; r < 4; ++r) pk.hh[r] = (bf16_t)sc[nt][r];
            *(uint2*)&myP[l15 * 72 + nt * 16 + quad * 4] = pk.u;
        }

        // O^T: o[dn] += mfma(A = V^T rows d, B = P^T cols q)  -> row = d, col = q = l15
        bf16x8 pb[2];
#pragma unroll
        for (int ks = 0; ks < 2; ++ks)
            pb[ks] = *(const bf16x8*)&myP[l15 * 72 + ks * 32 + quad * 8];
#pragma unroll
        for (int dn = 0; dn < 4; ++dn)
#pragma unroll
            for (int ks = 0; ks < 2; ++ks) {
                int rr = dn * 16 + l15;
                bf16x8 vf = *(const bf16x8*)&vtc[rr * 64 + (((ks * 4 + quad) ^ (l15 & 7)) * 8)];
                o[dn] = __builtin_amdgcn_mfma_f32_16x16x32_bf16(vf, pb[ks], o[dn], 0, 0, 0);
            }
    }

    // epilogue: lane (l15, quad) holds O^T[d = dn*16 + quad*4 + r][q = qrow]; write 8B packs
    float linv = 1.f / l_i;
    bf16_t* yb = y + ((size_t)(b * T + qt0 + qrow)) * C + h * 64;
#pragma unroll
    for (int dn = 0; dn < 4; ++dn) {
        union { bf16_t hh[4]; uint2 u; } pk;
#pragma unroll
        for (int r = 0; r < 4; ++r) pk.hh[r] = (bf16_t)(o[dn][r] * linv);
        *(uint2*)(yb + dn * 16 + quad * 4) = pk.u;
    }
}

// ---------------- host launch ----------------
extern "C" void kernel_launch(void* const* d_in, const int* in_sizes, int n_in,
                              void* d_out, int out_size, void* d_ws, size_t ws_size,
                              hipStream_t stream) {
    const float* x0  = (const float*)d_in[0];
    const float* wq  = (const float*)d_in[1];
    const float* bq  = (const float*)d_in[2];
    const float* wk  = (const float*)d_in[3];
    const float* bk  = (const float*)d_in[4];
    const float* wv  = (const float*)d_in[5];
    const float* bv  = (const float*)d_in[6];
    const float* wo  = (const float*)d_in[7];
    const float* bo  = (const float*)d_in[8];
    const float* rlk = (const float*)d_in[9];
    const float* g1  = (const float*)d_in[10];
    const float* be1 = (const float*)d_in[11];
    const float* w1  = (const float*)d_in[12];
    const float* bb1 = (const float*)d_in[13];
    const float* w2  = (const float*)d_in[14];
    const float* bb2 = (const float*)d_in[15];
    const float* g2  = (const float*)d_in[16];
    const float* be2 = (const float*)d_in[17];

    char* ws = (char*)d_ws;
    float*  xf    = (float*)(ws + OFF_XF);
    float*  yf    = (float*)(ws + OFF_YF);
    float*  yf2   = (float*)(ws + OFF_Q);       // aliases Q+K (dead at use time)
    float*  yf3   = (float*)(ws + OFF_VT);      // aliases VT+YA (dead during FFN2)
    bf16_t* xpad  = (bf16_t*)(ws + OFF_XPAD);
    bf16_t* qb    = (bf16_t*)(ws + OFF_Q);
    bf16_t* kb    = (bf16_t*)(ws + OFF_K);
    bf16_t* vTb   = (bf16_t*)(ws + OFF_VT);
    bf16_t* yab   = (bf16_t*)(ws + OFF_YA);
    bf16_t* midp  = (bf16_t*)(ws + OFF_MID);
    bf16_t* wqkvo = (bf16_t*)(ws + OFF_WQKVO);
    bf16_t* w1b   = (bf16_t*)(ws + OFF_W1);
    bf16_t* w2b   = (bf16_t*)(ws + OFF_W2);

    transpose_in<<<dim3(T / 32, C / 32, B), dim3(32, 8), 0, stream>>>(x0, xf, xpad);
    zero_pads<<<80, 256, 0, stream>>>(xpad, midp);

    for (int l = 0; l < L; ++l) {
        cvt4_kernel<<<4 * C * C / 256, 256, 0, stream>>>(wq + (size_t)l * C * C, wk + (size_t)l * C * C,
                                                         wv + (size_t)l * C * C, wo + (size_t)l * C * C, wqkvo);
        cvtw1_kernel<<<3 * FC * C / 256, 256, 0, stream>>>(w1 + (size_t)l * FC * C * 3, w1b);
        cvtw2_kernel<<<3 * C * FC / 256, 256, 0, stream>>>(w2 + (size_t)l * C * FC * 3, w2b);

        // fused QKV projection: N=1536, K=512 -> qb, kb, vT
        gemm128<3, false, 1, 8, 1><<<dim3(1536 / 128, T / 128, B), 256, 0, stream>>>(
            xpad + C, (long)(T + 2) * C, C, wqkvo, 0, C,
            bq + l * C, bk + l * C, bv + l * C,
            (void*)qb, (void*)kb, (void*)vTb, 0, 0);

        attn_kernel<<<dim3(T / 64, H, B), 256, 0, stream>>>(qb, kb, vTb, rlk + (size_t)l * 9 * KC, yab);

        // O projection, split-K x2 -> f32 partials yf, yf2
        gemm128<0, false, 2, 8, 1><<<dim3(C / 128, T / 128, 2 * B), 256, 0, stream>>>(
            yab, (long)T * C, C, wqkvo + 3 * C * C, 0, C,
            bo + l * C, nullptr, nullptr,
            (void*)yf, (void*)yf2, nullptr, (long)T * C, C);

        add_ln<2><<<B * T, 256, 0, stream>>>(xf, yf, yf2, nullptr, g1 + l * C, be1 + l * C, xpad);

        // FFN1: conv K=3 + bias + relu -> bf16 mid_pad rows 1..T
        gemm128<1, true, 1, 8, 3><<<dim3(FC / 128, T / 128, B), 256, 0, stream>>>(
            xpad, (long)(T + 2) * C, C, w1b, (long)FC * C, C,
            bb1 + l * FC, nullptr, nullptr,
            (void*)(midp + FC), nullptr, nullptr, (long)(T + 2) * FC, FC);

        // FFN2: conv K=3, split-K x3 (tap-aligned) -> f32 partials yf, yf2, yf3
        gemm128<0, false, 3, 32, 3><<<dim3(C / 128, T / 128, 3 * B), 256, 0, stream>>>(
            midp, (long)(T + 2) * FC, FC, w2b, (long)C * FC, FC,
            bb2 + l * C, nullptr, nullptr,
            (void*)yf, (void*)yf2, (void*)yf3, (long)T * C, C);

        add_ln<3><<<B * T, 256, 0, stream>>>(xf, yf, yf2, yf3, g2 + l * C, be2 + l * C, xpad);
    }

    transpose_out<<<dim3(T / 32, C / 32, B), dim3(32, 8), 0, stream>>>(xf, (float*)d_out);
}

// Round 5
// 1155.770 us; speedup vs baseline: 1.1628x; 1.0716x over previous
//
#include <hip/hip_runtime.h>

// ---------------- problem constants ----------------
constexpr int L  = 6;
constexpr int C  = 512;
constexpr int FC = 2048;
constexpr int H  = 8;
constexpr int KC = 64;
constexpr int T  = 1024;
constexpr int B  = 4;
#define SCALE 0.125f   // 1/sqrt(KC)
#define LOG2E 1.4426950408889634f

typedef __bf16 bf16_t;
typedef __bf16 bf16x8 __attribute__((ext_vector_type(8)));
typedef float  f32x4  __attribute__((ext_vector_type(4)));

// ---------------- workspace layout (bytes) ----------------
constexpr size_t OFF_XF    = 0;                               // f32 [B][T][C]      8 MB
constexpr size_t OFF_YF    = OFF_XF   + (size_t)B*T*C*4;      // f32 [B][T][C]      8 MB (partial 0)
constexpr size_t OFF_XPAD  = OFF_YF   + (size_t)B*T*C*4;      // bf16 [B][T+2][C]
constexpr size_t OFF_Q     = OFF_XPAD + (size_t)B*(T+2)*C*2;  // bf16 [B][T][C]  (alias: f32 partial 1 spans Q+K)
constexpr size_t OFF_K     = OFF_Q    + (size_t)B*T*C*2;
constexpr size_t OFF_VT    = OFF_K    + (size_t)B*T*C*2;      // bf16 [B][C][T]  (alias: f32 partial 2 spans VT+YA)
constexpr size_t OFF_YA    = OFF_VT   + (size_t)B*T*C*2;      // bf16 [B][T][C]
constexpr size_t OFF_MID   = OFF_YA   + (size_t)B*T*C*2;      // bf16 [B][T+2][FC]  16 MB
constexpr size_t OFF_WQKVO = OFF_MID  + (size_t)B*(T+2)*FC*2; // bf16 [4][C][C]
constexpr size_t OFF_W1    = OFF_WQKVO+ (size_t)4*C*C*2;      // bf16 [3][FC][C]
constexpr size_t OFF_W2    = OFF_W1   + (size_t)3*FC*C*2;     // bf16 [3][C][FC]
// total ~69.3 MB

// ---------------- async global->LDS (16B/lane) ----------------
__device__ __forceinline__ void gload_lds16(const bf16_t* g, bf16_t* l) {
    __builtin_amdgcn_global_load_lds((const __attribute__((address_space(1))) void*)g,
                                     (__attribute__((address_space(3))) void*)l, 16, 0, 0);
}

// ---------------- fused weight conversion (all three, block-uniform ranges) ----------------
__global__ __launch_bounds__(256) void cvt_all(const float* __restrict__ a,
                                               const float* __restrict__ bq_,
                                               const float* __restrict__ c,
                                               const float* __restrict__ d,
                                               const float* __restrict__ w1,
                                               const float* __restrict__ w2,
                                               bf16_t* __restrict__ wqkvo,
                                               bf16_t* __restrict__ w1b,
                                               bf16_t* __restrict__ w2b) {
    int i = blockIdx.x * 256 + threadIdx.x;
    constexpr int N4 = 4 * C * C;            // 1,048,576 (÷256)
    constexpr int NW1 = 3 * FC * C;          // 3,145,728 (÷256)
    if (i < N4) {
        int which = i >> 18;
        int idx   = i & ((1 << 18) - 1);
        const float* s = (which == 0) ? a : (which == 1) ? bq_ : (which == 2) ? c : d;
        wqkvo[i] = (bf16_t)s[idx];
    } else if (i < N4 + NW1) {
        int t = i - N4;                      // out [3][FC][C]
        int j = t >> 20;
        int rem = t & ((1 << 20) - 1);
        int fc = rem >> 9, cc = rem & 511;
        w1b[t] = (bf16_t)w1[fc * (C * 3) + cc * 3 + j];
    } else {
        int t = i - N4 - NW1;                // out [3][C][FC]
        int j = t >> 20;
        int rem = t & ((1 << 20) - 1);
        int cc = rem >> 11, fc = rem & 2047;
        w2b[t] = (bf16_t)w2[cc * (FC * 3) + fc * 3 + j];
    }
}

// ---------------- transpose in/out ----------------
__global__ __launch_bounds__(256) void transpose_in(const float* __restrict__ x0,
                                                    float* __restrict__ xf,
                                                    bf16_t* __restrict__ xpad) {
    __shared__ float tile[32][33];
    int b = blockIdx.z, t0 = blockIdx.x * 32, c0 = blockIdx.y * 32;
    int tx = threadIdx.x, ty = threadIdx.y;
#pragma unroll
    for (int j = 0; j < 4; ++j)
        tile[ty + j * 8][tx] = x0[((size_t)b * C + c0 + ty + j * 8) * T + t0 + tx];
    __syncthreads();
#pragma unroll
    for (int j = 0; j < 4; ++j) {
        float v = tile[tx][ty + j * 8];
        long t = t0 + ty + j * 8;
        xf[((size_t)b * T + t) * C + c0 + tx] = v;
        xpad[((size_t)b * (T + 2) + t + 1) * C + c0 + tx] = (bf16_t)v;
    }
}

__global__ __launch_bounds__(256) void transpose_out(const float* __restrict__ xf,
                                                     float* __restrict__ out) {
    __shared__ float tile[32][33];
    int b = blockIdx.z, t0 = blockIdx.x * 32, c0 = blockIdx.y * 32;
    int tx = threadIdx.x, ty = threadIdx.y;
#pragma unroll
    for (int j = 0; j < 4; ++j)
        tile[ty + j * 8][tx] = xf[((size_t)b * T + t0 + ty + j * 8) * C + c0 + tx];
    __syncthreads();
#pragma unroll
    for (int j = 0; j < 4; ++j)
        out[((size_t)b * C + c0 + ty + j * 8) * T + t0 + tx] = tile[tx][ty + j * 8];
}

// ---------------- zero conv pads ----------------
__global__ __launch_bounds__(256) void zero_pads(bf16_t* __restrict__ xpad, bf16_t* __restrict__ midp) {
    int i = blockIdx.x * 256 + threadIdx.x;
    if (i < 4096) {
        int b = i >> 10, r = (i >> 9) & 1, c = i & 511;
        xpad[((size_t)b * (T + 2) + (size_t)r * (T + 1)) * C + c] = (bf16_t)0.f;
    } else {
        int j = i - 4096;
        int b = j >> 12, r = (j >> 11) & 1, c = j & 2047;
        midp[((size_t)b * (T + 2) + (size_t)r * (T + 1)) * FC + c] = (bf16_t)0.f;
    }
}

// ---------------- residual + NP-partial sum + layernorm (channel dim) ----------------
template <int NP>
__global__ __launch_bounds__(256) void add_ln(float* __restrict__ x,
                                              const float* __restrict__ p0, const float* __restrict__ p1,
                                              const float* __restrict__ p2,
                                              const float* __restrict__ g, const float* __restrict__ be,
                                              bf16_t* __restrict__ xpad) {
    long bt = blockIdx.x;
    int tid = threadIdx.x;
    float* xr = x + bt * C;
    float v0 = xr[tid] + p0[bt * C + tid] + p1[bt * C + tid];
    float v1 = xr[tid + 256] + p0[bt * C + tid + 256] + p1[bt * C + tid + 256];
    if (NP == 3) { v0 += p2[bt * C + tid]; v1 += p2[bt * C + tid + 256]; }
    float s = v0 + v1, q = v0 * v0 + v1 * v1;
#pragma unroll
    for (int m = 1; m < 64; m <<= 1) { s += __shfl_xor(s, m); q += __shfl_xor(q, m); }
    __shared__ float ss[4], qq[4];
    int wid = tid >> 6;
    if ((tid & 63) == 0) { ss[wid] = s; qq[wid] = q; }
    __syncthreads();
    s = ss[0] + ss[1] + ss[2] + ss[3];
    q = qq[0] + qq[1] + qq[2] + qq[3];
    float mean = s * (1.f / C);
    float var = q * (1.f / C) - mean * mean;
    float rstd = rsqrtf(var + 1e-4f);
    float o0 = (v0 - mean) * rstd * g[tid] + be[tid];
    float o1 = (v1 - mean) * rstd * g[tid + 256] + be[tid + 256];
    xr[tid] = o0; xr[tid + 256] = o1;
    long b = bt >> 10, t = bt & (T - 1);
    bf16_t* xp = xpad + (b * (T + 2) + t + 1) * C;
    xp[tid] = (bf16_t)o0; xp[tid + 256] = (bf16_t)o1;
}

// ---------------- 128xBNT GEMM, BK=64, global_load_lds + XOR-swizzled LDS ----------------
// BNT=128: 4 waves in 2x2, acc[4][4].  BNT=64: 4 waves in 4x1 (32 M-rows each), acc[2][4].
// BNT=64 grids land on multiples of 256 blocks -> balanced CU load (fixes 1.5-blocks/CU tail).
template <int OUTMODE, bool RELU, int NSPLIT, int IPT, int NTAPS, int BNT>
__global__ __launch_bounds__(256) void gemm128(
    const bf16_t* __restrict__ A, long batchStrideA, int lda,
    const bf16_t* __restrict__ Bw, long tapStrideB, int ldb,
    const float* __restrict__ bias0, const float* __restrict__ bias1,
    const float* __restrict__ bias2,
    void* __restrict__ Dp, void* __restrict__ D1p, void* __restrict__ D2p,
    long batchStrideD, int ldd) {
    __shared__ bf16_t As[128 * 64];
    __shared__ bf16_t Bs[BNT * 64];
    constexpr int WAVES_Y = (BNT == 128) ? 2 : 4;
    constexpr int WM = 128 / WAVES_Y;       // M-rows per wave: 64 or 32
    constexpr int MT = WM / 16;             // 4 or 2
    constexpr int CPW = BNT / 32;           // B chunks per wave: 4 or 2
    const int tid = threadIdx.x;
    const int lane = tid & 63, wid = tid >> 6;
    const int l15 = lane & 15, quad = lane >> 4;
    const int wy = (BNT == 128) ? (wid >> 1) : wid;
    const int wx = (BNT == 128) ? (wid & 1) : 0;
    const int nb = gridDim.z / NSPLIT;
    const int split = (NSPLIT > 1) ? ((int)blockIdx.z / nb) : 0;
    const int b = (int)blockIdx.z - split * nb;

    const bf16_t* Ab = A + (long)b * batchStrideA + (long)blockIdx.y * 128 * lda;
    const bf16_t* Bb = Bw + (long)blockIdx.x * BNT * ldb;

    const int lrow = lane >> 3;
    const int lcolsw = ((lane & 7) ^ lrow) * 8;

    f32x4 acc[MT][4];
#pragma unroll
    for (int i = 0; i < MT; ++i)
#pragma unroll
        for (int j = 0; j < 4; ++j) acc[i][j] = (f32x4){0.f, 0.f, 0.f, 0.f};

    constexpr int itersAll = IPT * NTAPS;
    constexpr int per = itersAll / NSPLIT;
    const int it0 = split * per;

    for (int it = it0; it < it0 + per; ++it) {
        const int tap = (NTAPS == 1) ? 0 : (it / IPT);
        const int k0 = (it - tap * IPT) * 64;
        const bf16_t* At = Ab + (long)tap * lda + k0;
        const bf16_t* Bt = Bb + (long)tap * tapStrideB + k0;
        __syncthreads();
#pragma unroll
        for (int i = 0; i < 4; ++i) {           // A: 16 chunks of 8 rows
            int chunk = wid * 4 + i;
            int row = chunk * 8 + lrow;
            gload_lds16(At + (long)row * lda + lcolsw, As + chunk * 512 + lane * 8);
        }
#pragma unroll
        for (int i = 0; i < CPW; ++i) {         // B: BNT/8 chunks
            int chunk = wid * CPW + i;
            int row = chunk * 8 + lrow;
            gload_lds16(Bt + (long)row * ldb + lcolsw, Bs + chunk * 512 + lane * 8);
        }
        __syncthreads();
#pragma unroll
        for (int ks = 0; ks < 2; ++ks) {
            bf16x8 bfr[4], afr[MT];
#pragma unroll
            for (int nt = 0; nt < 4; ++nt) {
                int row = wx * 64 + nt * 16 + l15;
                bfr[nt] = *(const bf16x8*)&Bs[row * 64 + (((ks * 4 + quad) ^ (l15 & 7)) * 8)];
            }
#pragma unroll
            for (int mt = 0; mt < MT; ++mt) {
                int row = wy * WM + mt * 16 + l15;
                afr[mt] = *(const bf16x8*)&As[row * 64 + (((ks * 4 + quad) ^ (l15 & 7)) * 8)];
            }
#pragma unroll
            for (int mt = 0; mt < MT; ++mt)
#pragma unroll
                for (int nt = 0; nt < 4; ++nt)
                    acc[mt][nt] = __builtin_amdgcn_mfma_f32_16x16x32_bf16(afr[mt], bfr[nt], acc[mt][nt], 0, 0, 0);
        }
    }

    const long m0 = (long)blockIdx.y * 128 + wy * WM;
    const int n0g = (int)blockIdx.x * BNT + wx * 64;
#pragma unroll
    for (int mt = 0; mt < MT; ++mt) {
        long rowb = m0 + mt * 16 + quad * 4;
#pragma unroll
        for (int nt = 0; nt < 4; ++nt) {
            int col = n0g + nt * 16 + l15;
            if (OUTMODE == 0) {
                float bb = (split == 0) ? bias0[col] : 0.f;
                float* D = ((split == 0) ? (float*)Dp : (split == 1) ? (float*)D1p : (float*)D2p)
                           + (long)b * batchStrideD;
#pragma unroll
                for (int r = 0; r < 4; ++r) D[(rowb + r) * ldd + col] = acc[mt][nt][r] + bb;
            } else if (OUTMODE == 1) {
                float bb = bias0[col];
                bf16_t* D = (bf16_t*)Dp + (long)b * batchStrideD;
#pragma unroll
                for (int r = 0; r < 4; ++r) {
                    float v = acc[mt][nt][r] + bb;
                    if (RELU) v = fmaxf(v, 0.f);
                    D[(rowb + r) * ldd + col] = (bf16_t)v;
                }
            } else {  // QKV fused
                int which = col >> 9, cl = col & 511;
                const float* bp = (which == 0) ? bias0 : (which == 1) ? bias1 : bias2;
                float bb = bp[cl];
                if (which < 2) {
                    bf16_t* D = (bf16_t*)((which == 0) ? Dp : D1p) + (long)b * T * C;
#pragma unroll
                    for (int r = 0; r < 4; ++r) D[(rowb + r) * C + cl] = (bf16_t)(acc[mt][nt][r] + bb);
                } else {
                    bf16_t* D = (bf16_t*)D2p + (long)b * C * T;
                    union { bf16_t h[4]; uint2 u; } pk;
#pragma unroll
                    for (int r = 0; r < 4; ++r) pk.h[r] = (bf16_t)(acc[mt][nt][r] + bb);
                    *(uint2*)(D + (long)cl * T + rowb) = pk.u;
                }
            }
        }
    }
}

// ---------------- fused attention: swapped-operand (S^T / O^T) flash kernel ----------------
// grid (T/64, H, B), 256 thr. Wave owns Q rows wid*16..+15. Computes S^T = mfma(K,Q) so each
// lane holds 16 scores of ONE Q row (q = l15): softmax max/sum = in-register tree + 2 shfls;
// m/l/alpha are lane scalars. PV swapped too: O^T = mfma(V, P) — all LDS reads byte-identical
// to the non-swapped version. Rel-bias uniform (j=0 or 8) for 10/16 tiles -> register bias.
__global__ __launch_bounds__(256) void attn_kernel(const bf16_t* __restrict__ q,
                                                   const bf16_t* __restrict__ k,
                                                   const bf16_t* __restrict__ vT,
                                                   const float* __restrict__ relk,
                                                   bf16_t* __restrict__ y) {
    const int b = blockIdx.z, h = blockIdx.y;
    const int qt0 = blockIdx.x * 64;
    __shared__ bf16_t qps[64 * 72];      // swizzled Q [64][64] first, then P strips [8w][16][72]
    __shared__ bf16_t ktb[2][64 * 64];   // double-buffered swizzled K tiles
    __shared__ bf16_t vtb[2][64 * 64];   // double-buffered swizzled V^T tiles
    __shared__ float  rl[64][12];        // rel logits (exp2 domain)

    const int tid = threadIdx.x;
    const int lane = tid & 63, wid = tid >> 6;
    const int l15 = lane & 15, quad = lane >> 4;
    const int lrow = lane >> 3;                // 0..7 row within 8-row chunk
    const int su   = ((lane & 7) ^ lrow) * 8;  // swizzled source elem offset

    const bf16_t* qbase = q + ((size_t)(b * T + qt0)) * C + h * 64;
    const bf16_t* kbs = k + ((size_t)(b * T)) * C + h * 64;
    const bf16_t* vbs = vT + ((size_t)(b * C + h * 64)) * T;

    // prologue: stage Q + K/V tile 0, all async
#pragma unroll
    for (int i = 0; i < 2; ++i) {
        int chunk = wid * 2 + i;
        int row = chunk * 8 + lrow;
        gload_lds16(qbase + (long)row * C + su, qps + chunk * 512 + lane * 8);
        gload_lds16(kbs + (long)row * C + su, ktb[0] + chunk * 512 + lane * 8);
        gload_lds16(vbs + (long)row * T + su, vtb[0] + chunk * 512 + lane * 8);
    }
    __syncthreads();

    // rel logits: rl[r][j] = (SCALE*LOG2E) * q[r]·relk[j]   (reads swizzled qps)
    for (int i = tid; i < 64 * 9; i += 256) {
        int r = i / 9, j = i - r * 9;
        float acc = 0.f;
#pragma unroll
        for (int d = 0; d < 64; ++d)
            acc += (float)qps[r * 64 + ((d >> 3) ^ (r & 7)) * 8 + (d & 7)] * relk[j * 64 + d];
        rl[r][j] = acc * (SCALE * LOG2E);
    }
    __syncthreads();   // rl visible to all threads

    // Q fragments (B-operand role: col = q = l15 of wave's 16-row strip)
    const int qrow = wid * 16 + l15;
    bf16x8 af[2];
#pragma unroll
    for (int ks = 0; ks < 2; ++ks)
        af[ks] = *(const bf16x8*)&qps[qrow * 64 + (((ks * 4 + quad) ^ (qrow & 7)) * 8)];
    const float rl0 = rl[qrow][0], rl8 = rl[qrow][8];   // uniform-tile biases (register)

    float m_i = -1e30f, l_i = 0.f;   // lane-scalar online-softmax state (q = qrow)
    f32x4 o[4];
#pragma unroll
    for (int dn = 0; dn < 4; ++dn) o[dn] = (f32x4){0.f, 0.f, 0.f, 0.f};

    bf16_t* myP = qps + wid * (16 * 72);

    for (int st = 0; st < T / 64; ++st) {
        // barrier: stage(st) drained; prior reads of other dbuf done; (st==0) Q/rl phase done
        __syncthreads();
        if (st < T / 64 - 1) {
            const bf16_t* kb2 = kbs + (size_t)(st + 1) * 64 * C;
            const bf16_t* vb2 = vbs + (st + 1) * 64;
            bf16_t* kd = ktb[(st + 1) & 1];
            bf16_t* vd = vtb[(st + 1) & 1];
#pragma unroll
            for (int i = 0; i < 2; ++i) {
                int chunk = wid * 2 + i, row = chunk * 8 + lrow;
                gload_lds16(kb2 + (long)row * C + su, kd + chunk * 512 + lane * 8);
                gload_lds16(vb2 + (long)row * T + su, vd + chunk * 512 + lane * 8);
            }
        }
        const bf16_t* ktc = ktb[st & 1];
        const bf16_t* vtc = vtb[st & 1];

        // S^T tile: sc[nt][r] = S[s = nt*16 + quad*4 + r][q = l15]  (A=K, B=Q)
        f32x4 sc[4];
#pragma unroll
        for (int nt = 0; nt < 4; ++nt) {
            f32x4 a = (f32x4){0.f, 0.f, 0.f, 0.f};
#pragma unroll
            for (int ks = 0; ks < 2; ++ks) {
                int rr = nt * 16 + l15;
                bf16x8 kfr = *(const bf16x8*)&ktc[rr * 64 + (((ks * 4 + quad) ^ (l15 & 7)) * 8)];
                a = __builtin_amdgcn_mfma_f32_16x16x32_bf16(kfr, af[ks], a, 0, 0, 0);
            }
            sc[nt] = a;
        }

        // scale (exp2 domain) + rel bias.  d = s_g - q_g; j = clamp(d+4, 0, 8).
        const int base = st * 64 - qt0 - wid * 16;
        if (base >= 32) {
#pragma unroll
            for (int nt = 0; nt < 4; ++nt)
#pragma unroll
                for (int r = 0; r < 4; ++r) sc[nt][r] = sc[nt][r] * (SCALE * LOG2E) + rl8;
        } else if (base <= -80) {
#pragma unroll
            for (int nt = 0; nt < 4; ++nt)
#pragma unroll
                for (int r = 0; r < 4; ++r) sc[nt][r] = sc[nt][r] * (SCALE * LOG2E) + rl0;
        } else {
#pragma unroll
            for (int nt = 0; nt < 4; ++nt)
#pragma unroll
                for (int r = 0; r < 4; ++r) {
                    int j = base + nt * 16 + quad * 4 + r - l15 + 4;
                    j = j < 0 ? 0 : (j > 8 ? 8 : j);
                    sc[nt][r] = sc[nt][r] * (SCALE * LOG2E) + rl[qrow][j];
                }
        }

        // online softmax (base 2): 16 values in-lane + cross-quad combine (xor16, xor32)
        float mx = fmaxf(fmaxf(fmaxf(sc[0][0], sc[0][1]), fmaxf(sc[0][2], sc[0][3])),
                         fmaxf(fmaxf(sc[1][0], sc[1][1]), fmaxf(sc[1][2], sc[1][3])));
        mx = fmaxf(mx, fmaxf(fmaxf(fmaxf(sc[2][0], sc[2][1]), fmaxf(sc[2][2], sc[2][3])),
                             fmaxf(fmaxf(sc[3][0], sc[3][1]), fmaxf(sc[3][2], sc[3][3]))));
        mx = fmaxf(mx, __shfl_xor(mx, 16));
        mx = fmaxf(mx, __shfl_xor(mx, 32));
        float mn = fmaxf(m_i, mx);
        float alpha = exp2f(m_i - mn);
        m_i = mn;
        float rs = 0.f;
#pragma unroll
        for (int nt = 0; nt < 4; ++nt)
#pragma unroll
            for (int r = 0; r < 4; ++r) {
                float p = exp2f(sc[nt][r] - m_i);
                sc[nt][r] = p;
                rs += p;
            }
        rs += __shfl_xor(rs, 16);
        rs += __shfl_xor(rs, 32);
        l_i = l_i * alpha + rs;
#pragma unroll
        for (int dn = 0; dn < 4; ++dn) o[dn] *= alpha;

        // P strip: myP[q=l15][s] — packed 4 x ds_write_b64 (s = nt*16 + quad*4 + r)
#pragma unroll
        for (int nt = 0; nt < 4; ++nt) {
            union { bf16_t hh[4]; uint2 u; } pk;
#pragma unroll
            for (int r = 0; r < 4; ++r) pk.hh[r] = (bf16_t)sc[nt][r];
            *(uint2*)&myP[l15 * 72 + nt * 16 + quad * 4] = pk.u;
        }

        // O^T: o[dn] += mfma(A = V^T rows d, B = P^T cols q)  -> row = d, col = q = l15
        bf16x8 pb[2];
#pragma unroll
        for (int ks = 0; ks < 2; ++ks)
            pb[ks] = *(const bf16x8*)&myP[l15 * 72 + ks * 32 + quad * 8];
#pragma unroll
        for (int dn = 0; dn < 4; ++dn)
#pragma unroll
            for (int ks = 0; ks < 2; ++ks) {
                int rr = dn * 16 + l15;
                bf16x8 vf = *(const bf16x8*)&vtc[rr * 64 + (((ks * 4 + quad) ^ (l15 & 7)) * 8)];
                o[dn] = __builtin_amdgcn_mfma_f32_16x16x32_bf16(vf, pb[ks], o[dn], 0, 0, 0);
            }
    }

    // epilogue: lane (l15, quad) holds O^T[d = dn*16 + quad*4 + r][q = qrow]; write 8B packs
    float linv = 1.f / l_i;
    bf16_t* yb = y + ((size_t)(b * T + qt0 + qrow)) * C + h * 64;
#pragma unroll
    for (int dn = 0; dn < 4; ++dn) {
        union { bf16_t hh[4]; uint2 u; } pk;
#pragma unroll
        for (int r = 0; r < 4; ++r) pk.hh[r] = (bf16_t)(o[dn][r] * linv);
        *(uint2*)(yb + dn * 16 + quad * 4) = pk.u;
    }
}

// ---------------- host launch ----------------
extern "C" void kernel_launch(void* const* d_in, const int* in_sizes, int n_in,
                              void* d_out, int out_size, void* d_ws, size_t ws_size,
                              hipStream_t stream) {
    const float* x0  = (const float*)d_in[0];
    const float* wq  = (const float*)d_in[1];
    const float* bq  = (const float*)d_in[2];
    const float* wk  = (const float*)d_in[3];
    const float* bk  = (const float*)d_in[4];
    const float* wv  = (const float*)d_in[5];
    const float* bv  = (const float*)d_in[6];
    const float* wo  = (const float*)d_in[7];
    const float* bo  = (const float*)d_in[8];
    const float* rlk = (const float*)d_in[9];
    const float* g1  = (const float*)d_in[10];
    const float* be1 = (const float*)d_in[11];
    const float* w1  = (const float*)d_in[12];
    const float* bb1 = (const float*)d_in[13];
    const float* w2  = (const float*)d_in[14];
    const float* bb2 = (const float*)d_in[15];
    const float* g2  = (const float*)d_in[16];
    const float* be2 = (const float*)d_in[17];

    char* ws = (char*)d_ws;
    float*  xf    = (float*)(ws + OFF_XF);
    float*  yf    = (float*)(ws + OFF_YF);
    float*  yf2   = (float*)(ws + OFF_Q);       // aliases Q+K (dead at use time)
    float*  yf3   = (float*)(ws + OFF_VT);      // aliases VT+YA (dead during FFN2)
    bf16_t* xpad  = (bf16_t*)(ws + OFF_XPAD);
    bf16_t* qb    = (bf16_t*)(ws + OFF_Q);
    bf16_t* kb    = (bf16_t*)(ws + OFF_K);
    bf16_t* vTb   = (bf16_t*)(ws + OFF_VT);
    bf16_t* yab   = (bf16_t*)(ws + OFF_YA);
    bf16_t* midp  = (bf16_t*)(ws + OFF_MID);
    bf16_t* wqkvo = (bf16_t*)(ws + OFF_WQKVO);
    bf16_t* w1b   = (bf16_t*)(ws + OFF_W1);
    bf16_t* w2b   = (bf16_t*)(ws + OFF_W2);

    transpose_in<<<dim3(T / 32, C / 32, B), dim3(32, 8), 0, stream>>>(x0, xf, xpad);
    zero_pads<<<80, 256, 0, stream>>>(xpad, midp);

    constexpr int CVT_BLOCKS = (4 * C * C + 3 * FC * C + 3 * C * FC) / 256;

    for (int l = 0; l < L; ++l) {
        cvt_all<<<CVT_BLOCKS, 256, 0, stream>>>(wq + (size_t)l * C * C, wk + (size_t)l * C * C,
                                                wv + (size_t)l * C * C, wo + (size_t)l * C * C,
                                                w1 + (size_t)l * FC * C * 3, w2 + (size_t)l * C * FC * 3,
                                                wqkvo, w1b, w2b);

        // fused QKV projection: N=1536, K=512 -> qb, kb, vT   (BN=64: 768 blocks = 3/CU)
        gemm128<3, false, 1, 8, 1, 64><<<dim3(1536 / 64, T / 128, B), 256, 0, stream>>>(
            xpad + C, (long)(T + 2) * C, C, wqkvo, 0, C,
            bq + l * C, bk + l * C, bv + l * C,
            (void*)qb, (void*)kb, (void*)vTb, 0, 0);

        attn_kernel<<<dim3(T / 64, H, B), 256, 0, stream>>>(qb, kb, vTb, rlk + (size_t)l * 9 * KC, yab);

        // O projection, split-K x2 -> f32 partials yf, yf2   (BN=64: 512 blocks = 2/CU)
        gemm128<0, false, 2, 8, 1, 64><<<dim3(C / 64, T / 128, 2 * B), 256, 0, stream>>>(
            yab, (long)T * C, C, wqkvo + 3 * C * C, 0, C,
            bo + l * C, nullptr, nullptr,
            (void*)yf, (void*)yf2, nullptr, (long)T * C, C);

        add_ln<2><<<B * T, 256, 0, stream>>>(xf, yf, yf2, nullptr, g1 + l * C, be1 + l * C, xpad);

        // FFN1: conv K=3 + bias + relu -> bf16 mid_pad rows 1..T   (BN=128: 512 blocks, balanced)
        gemm128<1, true, 1, 8, 3, 128><<<dim3(FC / 128, T / 128, B), 256, 0, stream>>>(
            xpad, (long)(T + 2) * C, C, w1b, (long)FC * C, C,
            bb1 + l * FC, nullptr, nullptr,
            (void*)(midp + FC), nullptr, nullptr, (long)(T + 2) * FC, FC);

        // FFN2: conv K=3, split-K x3 (tap-aligned) -> f32 partials   (BN=64: 768 blocks = 3/CU)
        gemm128<0, false, 3, 32, 3, 64><<<dim3(C / 64, T / 128, 3 * B), 256, 0, stream>>>(
            midp, (long)(T + 2) * FC, FC, w2b, (long)C * FC, FC,
            bb2 + l * C, nullptr, nullptr,
            (void*)yf, (void*)yf2, (void*)yf3, (long)T * C, C);

        add_ln<3><<<B * T, 256, 0, stream>>>(xf, yf, yf2, yf3, g2 + l * C, be2 + l * C, xpad);
    }

    transpose_out<<<dim3(T / 32, C / 32, B), dim3(32, 8), 0, stream>>>(xf, (float*)d_out);
}